// Round 1
// baseline (1658.523 us; speedup 1.0000x reference)
//
#include <hip/hip_runtime.h>
#include <hip/hip_bf16.h>
#include <math.h>

#define T_CTX 2048
#define DM    2048
#define NQ    32
#define NKV   8
#define HD    64
#define QKV_LD 3072   // fused [T][Q(2048) | K(512) | V(512)]

// ---------------------------------------------------------------------------
// GEMM: C[M x N] = A[M x K] @ B[K x N] + bias, all f32 row-major.
// 128x128 tile, BK=16, 256 threads, 8x8 micro-tile per thread.
// M,N,K all multiples of tile dims for every call site (no bounds checks).
// ---------------------------------------------------------------------------
#define BM 128
#define BN 128
#define BK 16

__global__ __launch_bounds__(256) void gemm_bias_kernel(
    const float* __restrict__ A, const float* __restrict__ B,
    const float* __restrict__ bias, float* __restrict__ C,
    int K, int N, int ldc) {
  __shared__ float As[BK][BM + 4];   // stored transposed: As[k][m], pad->stride 132
  __shared__ float Bs[BK][BN + 4];
  const int bm = blockIdx.y * BM;
  const int bn = blockIdx.x * BN;
  const int tid = threadIdx.x;
  const int tm = (tid >> 4) * 8;
  const int tn = (tid & 15) * 8;

  float acc[8][8];
#pragma unroll
  for (int i = 0; i < 8; ++i)
#pragma unroll
    for (int j = 0; j < 8; ++j) acc[i][j] = 0.f;

  for (int k0 = 0; k0 < K; k0 += BK) {
    // A tile: 128 rows x 16 k. 512 float4 loads, transposed store into As[k][m].
#pragma unroll
    for (int i = 0; i < 2; ++i) {
      int idx = tid + i * 256;
      int row = idx >> 2;
      int c4 = (idx & 3) * 4;
      const float4 a = *(const float4*)(A + (size_t)(bm + row) * K + k0 + c4);
      As[c4 + 0][row] = a.x;
      As[c4 + 1][row] = a.y;
      As[c4 + 2][row] = a.z;
      As[c4 + 3][row] = a.w;
    }
    // B tile: 16 rows x 128 cols, row-major store (coalesced).
#pragma unroll
    for (int i = 0; i < 2; ++i) {
      int idx = tid + i * 256;
      int row = idx >> 5;
      int c4 = (idx & 31) * 4;
      *(float4*)(&Bs[row][c4]) = *(const float4*)(B + (size_t)(k0 + row) * N + bn + c4);
    }
    __syncthreads();
#pragma unroll
    for (int kk = 0; kk < BK; ++kk) {
      float a[8], b[8];
      *(float4*)(a)     = *(const float4*)(&As[kk][tm]);
      *(float4*)(a + 4) = *(const float4*)(&As[kk][tm + 4]);
      *(float4*)(b)     = *(const float4*)(&Bs[kk][tn]);
      *(float4*)(b + 4) = *(const float4*)(&Bs[kk][tn + 4]);
#pragma unroll
      for (int i = 0; i < 8; ++i)
#pragma unroll
        for (int j = 0; j < 8; ++j)
          acc[i][j] = fmaf(a[i], b[j], acc[i][j]);
    }
    __syncthreads();
  }

  float bb[8];
#pragma unroll
  for (int j = 0; j < 8; ++j) bb[j] = bias[bn + tn + j];
#pragma unroll
  for (int i = 0; i < 8; ++i) {
    float4 v0, v1;
    v0.x = acc[i][0] + bb[0]; v0.y = acc[i][1] + bb[1];
    v0.z = acc[i][2] + bb[2]; v0.w = acc[i][3] + bb[3];
    v1.x = acc[i][4] + bb[4]; v1.y = acc[i][5] + bb[5];
    v1.z = acc[i][6] + bb[6]; v1.w = acc[i][7] + bb[7];
    float* cp = C + (size_t)(bm + tm + i) * ldc + bn + tn;
    *(float4*)(cp)     = v0;
    *(float4*)(cp + 4) = v1;
  }
}

// ---------------------------------------------------------------------------
// RoPE in-place on Q (heads 0..31) and K (heads 32..39) columns of qkv buffer.
// pair (i, i+32) within each 64-dim head, freq = freqs[t*32 + i].
// ---------------------------------------------------------------------------
__global__ __launch_bounds__(256) void rope_kernel(float* __restrict__ qkv,
                                                   const float* __restrict__ freqs) {
  const int idx = blockIdx.x * 256 + threadIdx.x;   // t * 40 heads * 32 pairs
  const int i = idx & 31;
  const int h = (idx >> 5) % 40;
  const int t = idx / (40 * 32);
  const int base = (h < 32) ? h * HD : DM + (h - 32) * HD;
  float* p = qkv + (size_t)t * QKV_LD + base;
  const float f = freqs[t * 32 + i];
  float s, c;
  sincosf(f, &s, &c);
  const float x1 = p[i];
  const float x2 = p[i + 32];
  p[i]      = x1 * c - x2 * s;
  p[i + 32] = x1 * s + x2 * c;
}

// ---------------------------------------------------------------------------
// Flash-style causal GQA attention, f32.
// Grid (NQ heads, T/64 query-blocks), 256 threads.
// Thread layout: row r = tid>>2 (64 q rows), dim-chunk c = tid&3 (16 dims each).
// K/V tiles (64x64) staged in LDS; P tile in LDS for the PV step.
// Online softmax with per-row (m,l) replicated across the row's 4 lanes.
// ---------------------------------------------------------------------------
__global__ __launch_bounds__(256) void attn_kernel(const float* __restrict__ qkv,
                                                   float* __restrict__ O) {
  const int head = blockIdx.x;
  const int qb = blockIdx.y;
  const int kvh = head >> 2;        // GQA: 4 q heads per kv head
  const int tid = threadIdx.x;
  const int r = tid >> 2;
  const int c = tid & 3;
  const int cbase = c * 16;
  const int qrow = qb * 64 + r;

  __shared__ float Kt[64][HD + 4];  // pad -> row stride 68 floats (272B, 16B-aligned)
  __shared__ float Vt[64][HD + 4];
  __shared__ float Pt[64][65];      // pad 65 so PV reads (stride-65 rows) are conflict-free

  float q[16];
  {
    const float* qp = qkv + (size_t)qrow * QKV_LD + head * HD + cbase;
#pragma unroll
    for (int i = 0; i < 16; i += 4) {
      float4 t4 = *(const float4*)(qp + i);
      q[i]     = t4.x * 0.125f;   // fold scale = 1/sqrt(64) into Q
      q[i + 1] = t4.y * 0.125f;
      q[i + 2] = t4.z * 0.125f;
      q[i + 3] = t4.w * 0.125f;
    }
  }
  float o_acc[16];
#pragma unroll
  for (int i = 0; i < 16; ++i) o_acc[i] = 0.f;
  float m = -INFINITY, l = 0.f;

  const float* Kg = qkv + DM + (size_t)kvh * HD;
  const float* Vg = qkv + DM + NKV * HD + (size_t)kvh * HD;

  for (int kt = 0; kt <= qb; ++kt) {
    const int s0 = kt * 64;
    __syncthreads();   // previous iteration's reads of Kt/Vt are done
#pragma unroll
    for (int i = 0; i < 4; ++i) {
      int idx = tid + i * 256;        // 1024 float4 per matrix
      int row = idx >> 4;
      int c4 = (idx & 15) * 4;
      *(float4*)(&Kt[row][c4]) = *(const float4*)(Kg + (size_t)(s0 + row) * QKV_LD + c4);
      *(float4*)(&Vt[row][c4]) = *(const float4*)(Vg + (size_t)(s0 + row) * QKV_LD + c4);
    }
    __syncthreads();

    const bool diag = (kt == qb);
    float sc[16];
    // scores: every s computed by the row's 4 lanes (16 dims each) + shfl reduce;
    // lane keeps the 16 scores with s in its own chunk.
#pragma unroll
    for (int cc = 0; cc < 4; ++cc) {
#pragma unroll
      for (int j = 0; j < 16; ++j) {
        const int s = cc * 16 + j;
        float v = 0.f;
#pragma unroll
        for (int i = 0; i < 16; i += 4) {
          float4 t4 = *(const float4*)(&Kt[s][cbase + i]);
          v = fmaf(q[i],     t4.x, v);
          v = fmaf(q[i + 1], t4.y, v);
          v = fmaf(q[i + 2], t4.z, v);
          v = fmaf(q[i + 3], t4.w, v);
        }
        v += __shfl_xor(v, 1);
        v += __shfl_xor(v, 2);
        if (diag && (s0 + s > qrow)) v = -INFINITY;
        if (cc == c) sc[j] = v;
      }
    }
    // online softmax (m,l replicated in all 4 lanes of the row)
    float tmax = sc[0];
#pragma unroll
    for (int j = 1; j < 16; ++j) tmax = fmaxf(tmax, sc[j]);
    tmax = fmaxf(tmax, __shfl_xor(tmax, 1));
    tmax = fmaxf(tmax, __shfl_xor(tmax, 2));
    const float m_new = fmaxf(m, tmax);
    const float corr = __expf(m - m_new);   // m=-inf first tile -> corr=0
    l *= corr;
#pragma unroll
    for (int i = 0; i < 16; ++i) o_acc[i] *= corr;
    float lsum = 0.f;
    float p[16];
#pragma unroll
    for (int j = 0; j < 16; ++j) {
      p[j] = __expf(sc[j] - m_new);   // masked -inf -> 0
      lsum += p[j];
    }
    lsum += __shfl_xor(lsum, 1);
    lsum += __shfl_xor(lsum, 2);
    l += lsum;
#pragma unroll
    for (int j = 0; j < 16; ++j) Pt[r][cbase + j] = p[j];
    // PV: P row is written/read by the same 4 lanes (same wave) -> LDS program
    // order suffices, no barrier needed. Vt guarded by the staging barrier.
#pragma unroll 8
    for (int s = 0; s < 64; ++s) {
      const float pv = Pt[r][s];
#pragma unroll
      for (int i = 0; i < 16; i += 4) {
        float4 t4 = *(const float4*)(&Vt[s][cbase + i]);
        o_acc[i]     = fmaf(pv, t4.x, o_acc[i]);
        o_acc[i + 1] = fmaf(pv, t4.y, o_acc[i + 1]);
        o_acc[i + 2] = fmaf(pv, t4.z, o_acc[i + 2]);
        o_acc[i + 3] = fmaf(pv, t4.w, o_acc[i + 3]);
      }
    }
    m = m_new;
  }

  const float inv = 1.f / l;
  float* op = O + (size_t)qrow * DM + head * HD + cbase;
#pragma unroll
  for (int i = 0; i < 16; i += 4) {
    float4 t4;
    t4.x = o_acc[i]     * inv;
    t4.y = o_acc[i + 1] * inv;
    t4.z = o_acc[i + 2] * inv;
    t4.w = o_acc[i + 3] * inv;
    *(float4*)(op + i) = t4;
  }
}

// ---------------------------------------------------------------------------
extern "C" void kernel_launch(void* const* d_in, const int* in_sizes, int n_in,
                              void* d_out, int out_size, void* d_ws, size_t ws_size,
                              hipStream_t stream) {
  const float* x     = (const float*)d_in[0];
  const float* Wq    = (const float*)d_in[1];
  const float* bq    = (const float*)d_in[2];
  const float* Wk    = (const float*)d_in[3];
  const float* bk    = (const float*)d_in[4];
  const float* Wv    = (const float*)d_in[5];
  const float* bv    = (const float*)d_in[6];
  const float* Wo    = (const float*)d_in[7];
  const float* bo    = (const float*)d_in[8];
  const float* freqs = (const float*)d_in[9];
  float* out = (float*)d_out;

  float* qkv  = (float*)d_ws;                      // [2048][3072] f32 = 25.2 MB
  float* obuf = qkv + (size_t)T_CTX * QKV_LD;      // [2048][2048] f32 = 16.8 MB

  const dim3 blk(256);
  // QKV projections into fused buffer (ldc = 3072)
  gemm_bias_kernel<<<dim3(DM / BN, T_CTX / BM), blk, 0, stream>>>(
      x, Wq, bq, qkv, DM, DM, QKV_LD);
  gemm_bias_kernel<<<dim3(512 / BN, T_CTX / BM), blk, 0, stream>>>(
      x, Wk, bk, qkv + DM, DM, 512, QKV_LD);
  gemm_bias_kernel<<<dim3(512 / BN, T_CTX / BM), blk, 0, stream>>>(
      x, Wv, bv, qkv + DM + NKV * HD, DM, 512, QKV_LD);
  // RoPE on Q + K in place
  rope_kernel<<<(T_CTX * 40 * 32) / 256, blk, 0, stream>>>(qkv, freqs);
  // causal GQA attention -> obuf [2048][2048]
  attn_kernel<<<dim3(NQ, T_CTX / 64), blk, 0, stream>>>(qkv, obuf);
  // output projection -> d_out
  gemm_bias_kernel<<<dim3(DM / BN, T_CTX / BM), blk, 0, stream>>>(
      obuf, Wo, bo, out, DM, DM, DM);
}

// Round 3
// 769.286 us; speedup vs baseline: 2.1559x; 2.1559x over previous
//
#include <hip/hip_runtime.h>
#include <hip/hip_bf16.h>
#include <math.h>

#define T_CTX 2048
#define DM    2048
#define NQ    32
#define NKV   8
#define HD    64
#define QKV_LD 3072   // fused [T][Q(2048) | K(512) | V(512)]

typedef __attribute__((ext_vector_type(8))) short short8;     // 8 bf16 = 4 VGPR
typedef __attribute__((ext_vector_type(4))) float floatx4;    // MFMA acc

// ---------------------------------------------------------------------------
// cast f32 -> bf16, 8 elems/thread
// ---------------------------------------------------------------------------
__global__ __launch_bounds__(256) void cast_bf16_kernel(const float* __restrict__ src,
                                                        __hip_bfloat16* __restrict__ dst) {
  const int i = blockIdx.x * 256 + threadIdx.x;
  const float4 a = ((const float4*)src)[2 * i];
  const float4 b = ((const float4*)src)[2 * i + 1];
  union { ushort u[8]; short8 v; } o;
  __hip_bfloat16 h;
  h = __float2bfloat16(a.x); o.u[0] = *(ushort*)&h;
  h = __float2bfloat16(a.y); o.u[1] = *(ushort*)&h;
  h = __float2bfloat16(a.z); o.u[2] = *(ushort*)&h;
  h = __float2bfloat16(a.w); o.u[3] = *(ushort*)&h;
  h = __float2bfloat16(b.x); o.u[4] = *(ushort*)&h;
  h = __float2bfloat16(b.y); o.u[5] = *(ushort*)&h;
  h = __float2bfloat16(b.z); o.u[6] = *(ushort*)&h;
  h = __float2bfloat16(b.w); o.u[7] = *(ushort*)&h;
  ((short8*)dst)[i] = o.v;
}

// ---------------------------------------------------------------------------
// transpose + cast: src f32 [Krows][Ncols] -> dst bf16 [Ncols][Krows]
// (dst row stride = Krows). 64x64 tiles, LDS f32 [64][65] (conflict-free).
// ---------------------------------------------------------------------------
__global__ __launch_bounds__(256) void transpose_cast_kernel(
    const float* __restrict__ src, __hip_bfloat16* __restrict__ dst,
    int Ncols, int Krows) {
  __shared__ float tile[64][65];
  const int n0 = blockIdx.x * 64;
  const int k0 = blockIdx.y * 64;
  const int c = threadIdx.x & 63;
  const int r0 = threadIdx.x >> 6;
#pragma unroll
  for (int s = 0; s < 16; ++s) {
    int r = r0 + 4 * s;
    tile[r][c] = src[(size_t)(k0 + r) * Ncols + n0 + c];
  }
  __syncthreads();
#pragma unroll
  for (int s = 0; s < 16; ++s) {
    int r = r0 + 4 * s;
    dst[(size_t)(n0 + r) * Krows + k0 + c] = __float2bfloat16(tile[c][r]);
  }
}

// ---------------------------------------------------------------------------
// bf16 MFMA GEMM: C[M][ldc] f32 = A[M][K]bf16 @ Bt[N][K]bf16^T + bias
// 128x128 tile, BK=64, 256 thr = 4 waves (2x2), 64x64 per wave, acc 4x4 frags.
// LDS rows are 128B -> XOR swizzle byte ^= ((row&7)<<4) on write AND read
// (G4: unswizzled would be a 16-way bank conflict on the fragment reads).
// ---------------------------------------------------------------------------
__global__ __launch_bounds__(256) void gemm_mfma_bt(
    const __hip_bfloat16* __restrict__ A, const __hip_bfloat16* __restrict__ Bt,
    const float* __restrict__ bias, float* __restrict__ C, int K, int ldc) {
  __shared__ alignas(16) short As[128 * 64];
  __shared__ alignas(16) short Bs[128 * 64];
  const int tid = threadIdx.x;
  const int lane = tid & 63;
  const int w = tid >> 6;
  const int wr = w >> 1, wc = w & 1;
  const int bm = blockIdx.y * 128, bn = blockIdx.x * 128;

  floatx4 zero4 = {0.f, 0.f, 0.f, 0.f};
  floatx4 acc[4][4];
#pragma unroll
  for (int m = 0; m < 4; ++m)
#pragma unroll
    for (int n = 0; n < 4; ++n) acc[m][n] = zero4;

  const int sr = tid >> 3;              // staging row base (0..31)
  const int skb = (tid & 7) * 16;       // byte offset within 128B row
  const int frag_kb = (lane >> 4) * 16; // fragment k-byte base within 64B half

  for (int k0 = 0; k0 < K; k0 += 64) {
    __syncthreads();
#pragma unroll
    for (int p = 0; p < 4; ++p) {
      const int r = sr + p * 32;
      const short8 av = *(const short8*)((const char*)(A + (size_t)(bm + r) * K + k0) + skb);
      const short8 bv = *(const short8*)((const char*)(Bt + (size_t)(bn + r) * K + k0) + skb);
      const int dst = r * 128 + (skb ^ ((r & 7) << 4));
      *(short8*)((char*)As + dst) = av;
      *(short8*)((char*)Bs + dst) = bv;
    }
    __syncthreads();
#pragma unroll
    for (int h = 0; h < 2; ++h) {
      short8 af[4], bf[4];
      const int kb = h * 64 + frag_kb;
#pragma unroll
      for (int m = 0; m < 4; ++m) {
        const int ar = wr * 64 + m * 16 + (lane & 15);
        af[m] = *(const short8*)((const char*)As + ar * 128 + (kb ^ ((ar & 7) << 4)));
      }
#pragma unroll
      for (int n = 0; n < 4; ++n) {
        const int br = wc * 64 + n * 16 + (lane & 15);
        bf[n] = *(const short8*)((const char*)Bs + br * 128 + (kb ^ ((br & 7) << 4)));
      }
#pragma unroll
      for (int m = 0; m < 4; ++m)
#pragma unroll
        for (int n = 0; n < 4; ++n)
          acc[m][n] = __builtin_amdgcn_mfma_f32_16x16x32_bf16(af[m], bf[n], acc[m][n], 0, 0, 0);
    }
  }

  // epilogue: C/D layout col=lane&15, row=(lane>>4)*4+reg  [m89 verified]
  const int col_l = lane & 15;
  const int row_l = (lane >> 4) * 4;
#pragma unroll
  for (int n = 0; n < 4; ++n) {
    const int col = bn + wc * 64 + n * 16 + col_l;
    const float bv = bias[col];
#pragma unroll
    for (int m = 0; m < 4; ++m) {
      const int row0 = bm + wr * 64 + m * 16 + row_l;
#pragma unroll
      for (int r2 = 0; r2 < 4; ++r2)
        C[(size_t)(row0 + r2) * ldc + col] = acc[m][n][r2] + bv;
    }
  }
}

// ---------------------------------------------------------------------------
// RoPE in-place on Q (heads 0..31) and K (heads 32..39) of fused qkv (f32).
// ---------------------------------------------------------------------------
__global__ __launch_bounds__(256) void rope_kernel(float* __restrict__ qkv,
                                                   const float* __restrict__ freqs) {
  const int idx = blockIdx.x * 256 + threadIdx.x;
  const int i = idx & 31;
  const int h = (idx >> 5) % 40;
  const int t = idx / (40 * 32);
  const int base = (h < 32) ? h * HD : DM + (h - 32) * HD;
  float* p = qkv + (size_t)t * QKV_LD + base;
  const float f = freqs[t * 32 + i];
  float s, c;
  sincosf(f, &s, &c);
  const float x1 = p[i];
  const float x2 = p[i + 32];
  p[i]      = x1 * c - x2 * s;
  p[i + 32] = x1 * s + x2 * c;
}

// ---------------------------------------------------------------------------
// Flash-style causal GQA attention, f32 compute, bf16 output (feeds out-proj).
// ---------------------------------------------------------------------------
__global__ __launch_bounds__(256) void attn_kernel(const float* __restrict__ qkv,
                                                   __hip_bfloat16* __restrict__ O) {
  const int head = blockIdx.x;
  const int qb = blockIdx.y;
  const int kvh = head >> 2;
  const int tid = threadIdx.x;
  const int r = tid >> 2;
  const int c = tid & 3;
  const int cbase = c * 16;
  const int qrow = qb * 64 + r;

  __shared__ float Kt[64][HD + 4];
  __shared__ float Vt[64][HD + 4];
  __shared__ float Pt[64][65];

  float q[16];
  {
    const float* qp = qkv + (size_t)qrow * QKV_LD + head * HD + cbase;
#pragma unroll
    for (int i = 0; i < 16; i += 4) {
      float4 t4 = *(const float4*)(qp + i);
      q[i]     = t4.x * 0.125f;
      q[i + 1] = t4.y * 0.125f;
      q[i + 2] = t4.z * 0.125f;
      q[i + 3] = t4.w * 0.125f;
    }
  }
  float o_acc[16];
#pragma unroll
  for (int i = 0; i < 16; ++i) o_acc[i] = 0.f;
  float m = -INFINITY, l = 0.f;

  const float* Kg = qkv + DM + (size_t)kvh * HD;
  const float* Vg = qkv + DM + NKV * HD + (size_t)kvh * HD;

  for (int kt = 0; kt <= qb; ++kt) {
    const int s0 = kt * 64;
    __syncthreads();
#pragma unroll
    for (int i = 0; i < 4; ++i) {
      int idx = tid + i * 256;
      int row = idx >> 4;
      int c4 = (idx & 15) * 4;
      *(float4*)(&Kt[row][c4]) = *(const float4*)(Kg + (size_t)(s0 + row) * QKV_LD + c4);
      *(float4*)(&Vt[row][c4]) = *(const float4*)(Vg + (size_t)(s0 + row) * QKV_LD + c4);
    }
    __syncthreads();

    const bool diag = (kt == qb);
    float sc[16];
#pragma unroll
    for (int cc = 0; cc < 4; ++cc) {
#pragma unroll
      for (int j = 0; j < 16; ++j) {
        const int s = cc * 16 + j;
        float v = 0.f;
#pragma unroll
        for (int i = 0; i < 16; i += 4) {
          float4 t4 = *(const float4*)(&Kt[s][cbase + i]);
          v = fmaf(q[i],     t4.x, v);
          v = fmaf(q[i + 1], t4.y, v);
          v = fmaf(q[i + 2], t4.z, v);
          v = fmaf(q[i + 3], t4.w, v);
        }
        v += __shfl_xor(v, 1);
        v += __shfl_xor(v, 2);
        if (diag && (s0 + s > qrow)) v = -INFINITY;
        if (cc == c) sc[j] = v;
      }
    }
    float tmax = sc[0];
#pragma unroll
    for (int j = 1; j < 16; ++j) tmax = fmaxf(tmax, sc[j]);
    tmax = fmaxf(tmax, __shfl_xor(tmax, 1));
    tmax = fmaxf(tmax, __shfl_xor(tmax, 2));
    const float m_new = fmaxf(m, tmax);
    const float corr = __expf(m - m_new);
    l *= corr;
#pragma unroll
    for (int i = 0; i < 16; ++i) o_acc[i] *= corr;
    float lsum = 0.f;
    float p[16];
#pragma unroll
    for (int j = 0; j < 16; ++j) {
      p[j] = __expf(sc[j] - m_new);
      lsum += p[j];
    }
    lsum += __shfl_xor(lsum, 1);
    lsum += __shfl_xor(lsum, 2);
    l += lsum;
#pragma unroll
    for (int j = 0; j < 16; ++j) Pt[r][cbase + j] = p[j];
#pragma unroll 8
    for (int s = 0; s < 64; ++s) {
      const float pv = Pt[r][s];
#pragma unroll
      for (int i = 0; i < 16; i += 4) {
        float4 t4 = *(const float4*)(&Vt[s][cbase + i]);
        o_acc[i]     = fmaf(pv, t4.x, o_acc[i]);
        o_acc[i + 1] = fmaf(pv, t4.y, o_acc[i + 1]);
        o_acc[i + 2] = fmaf(pv, t4.z, o_acc[i + 2]);
        o_acc[i + 3] = fmaf(pv, t4.w, o_acc[i + 3]);
      }
    }
    m = m_new;
  }

  const float inv = 1.f / l;
  __hip_bfloat16* op = O + (size_t)qrow * DM + head * HD + cbase;
#pragma unroll
  for (int i = 0; i < 16; ++i) op[i] = __float2bfloat16(o_acc[i] * inv);
}

// ---------------------------------------------------------------------------
extern "C" void kernel_launch(void* const* d_in, const int* in_sizes, int n_in,
                              void* d_out, int out_size, void* d_ws, size_t ws_size,
                              hipStream_t stream) {
  const float* x     = (const float*)d_in[0];
  const float* Wq    = (const float*)d_in[1];
  const float* bq    = (const float*)d_in[2];
  const float* Wk    = (const float*)d_in[3];
  const float* bk    = (const float*)d_in[4];
  const float* Wv    = (const float*)d_in[5];
  const float* bv    = (const float*)d_in[6];
  const float* Wo    = (const float*)d_in[7];
  const float* bo    = (const float*)d_in[8];
  const float* freqs = (const float*)d_in[9];
  float* out = (float*)d_out;

  // ws layout (peak 46.2 MB):
  //   [0)                qkv f32 [2048][3072]            25,165,824 B
  //   [25,165,824)       Wt  bf16 [3072][2048] (QKV^T)   12,582,912 B  -> reused for Wo^T
  //   [37,748,736)       xb  bf16 [2048][2048]            8,388,608 B  -> reused for attn out
  //   [46,137,344)       bias_cat f32 [3072]                 12,288 B
  char* ws = (char*)d_ws;
  float*          qkv  = (float*)ws;
  __hip_bfloat16* wt   = (__hip_bfloat16*)(ws + 25165824);
  __hip_bfloat16* xb   = (__hip_bfloat16*)(ws + 37748736);
  __hip_bfloat16* obuf = xb;  // alias: xb dead after QKV GEMM
  __hip_bfloat16* wot  = wt;  // alias: wt dead after QKV GEMM
  float*          bcat = (float*)(ws + 46137344);

  const dim3 blk(256);

  // --- prep: casts + weight transposes + fused bias ---
  cast_bf16_kernel<<<(DM * T_CTX) / (256 * 8), blk, 0, stream>>>(x, xb);
  transpose_cast_kernel<<<dim3(32, 32), blk, 0, stream>>>(Wq, wt, 2048, 2048);
  transpose_cast_kernel<<<dim3(8, 32),  blk, 0, stream>>>(Wk, wt + (size_t)2048 * 2048, 512, 2048);
  transpose_cast_kernel<<<dim3(8, 32),  blk, 0, stream>>>(Wv, wt + (size_t)2560 * 2048, 512, 2048);
  hipMemcpyAsync(bcat,        bq, 2048 * 4, hipMemcpyDeviceToDevice, stream);
  hipMemcpyAsync(bcat + 2048, bk, 512 * 4,  hipMemcpyDeviceToDevice, stream);
  hipMemcpyAsync(bcat + 2560, bv, 512 * 4,  hipMemcpyDeviceToDevice, stream);

  // --- fused QKV projection: [2048][2048] @ [2048][3072] -> qkv (ldc 3072) ---
  gemm_mfma_bt<<<dim3(3072 / 128, 2048 / 128), blk, 0, stream>>>(
      xb, wt, bcat, qkv, DM, QKV_LD);

  // --- RoPE on Q + K in place (f32) ---
  rope_kernel<<<(T_CTX * 40 * 32) / 256, blk, 0, stream>>>(qkv, freqs);

  // --- Wo^T (reuses wt region; stream-ordered after QKV GEMM) ---
  transpose_cast_kernel<<<dim3(32, 32), blk, 0, stream>>>(Wo, wot, 2048, 2048);

  // --- causal GQA attention -> obuf bf16 [2048][2048] ---
  attn_kernel<<<dim3(NQ, T_CTX / 64), blk, 0, stream>>>(qkv, obuf);

  // --- output projection: obuf @ Wo + bo -> d_out (f32) ---
  gemm_mfma_bt<<<dim3(2048 / 128, 2048 / 128), blk, 0, stream>>>(
      obuf, wot, bo, out, DM, DM);
}

// Round 4
// 331.383 us; speedup vs baseline: 5.0048x; 2.3214x over previous
//
#include <hip/hip_runtime.h>
#include <hip/hip_bf16.h>
#include <math.h>

#define T_CTX 2048
#define DM    2048
#define NQ    32
#define NKV   8
#define HD    64
#define QKV_LD 3072   // fused [T][Q(2048) | K(512) | V(512)] bf16

typedef __attribute__((ext_vector_type(8))) short short8;     // 8 bf16 = 4 VGPR
typedef __attribute__((ext_vector_type(4))) float floatx4;    // MFMA acc

// ---------------------------------------------------------------------------
// cast f32 -> bf16, 8 elems/thread
// ---------------------------------------------------------------------------
__global__ __launch_bounds__(256) void cast_bf16_kernel(const float* __restrict__ src,
                                                        __hip_bfloat16* __restrict__ dst) {
  const int i = blockIdx.x * 256 + threadIdx.x;
  const float4 a = ((const float4*)src)[2 * i];
  const float4 b = ((const float4*)src)[2 * i + 1];
  union { ushort u[8]; short8 v; } o;
  __hip_bfloat16 h;
  h = __float2bfloat16(a.x); o.u[0] = *(ushort*)&h;
  h = __float2bfloat16(a.y); o.u[1] = *(ushort*)&h;
  h = __float2bfloat16(a.z); o.u[2] = *(ushort*)&h;
  h = __float2bfloat16(a.w); o.u[3] = *(ushort*)&h;
  h = __float2bfloat16(b.x); o.u[4] = *(ushort*)&h;
  h = __float2bfloat16(b.y); o.u[5] = *(ushort*)&h;
  h = __float2bfloat16(b.z); o.u[6] = *(ushort*)&h;
  h = __float2bfloat16(b.w); o.u[7] = *(ushort*)&h;
  ((short8*)dst)[i] = o.v;
}

// ---------------------------------------------------------------------------
// transpose + cast: src f32 [Krows][Ncols] -> dst bf16 [Ncols][Krows]
// ---------------------------------------------------------------------------
__global__ __launch_bounds__(256) void transpose_cast_kernel(
    const float* __restrict__ src, __hip_bfloat16* __restrict__ dst,
    int Ncols, int Krows) {
  __shared__ float tile[64][65];
  const int n0 = blockIdx.x * 64;
  const int k0 = blockIdx.y * 64;
  const int c = threadIdx.x & 63;
  const int r0 = threadIdx.x >> 6;
#pragma unroll
  for (int s = 0; s < 16; ++s) {
    int r = r0 + 4 * s;
    tile[r][c] = src[(size_t)(k0 + r) * Ncols + n0 + c];
  }
  __syncthreads();
#pragma unroll
  for (int s = 0; s < 16; ++s) {
    int r = r0 + 4 * s;
    dst[(size_t)(n0 + r) * Krows + k0 + c] = __float2bfloat16(tile[c][r]);
  }
}

// ---------------------------------------------------------------------------
// bf16 MFMA GEMM (verified R3): C[M][ldc] = A[M][K]bf16 @ Bt[N][K]^T + bias.
// OutT = float or __hip_bfloat16.
// ---------------------------------------------------------------------------
template <typename OutT>
__global__ __launch_bounds__(256) void gemm_mfma_bt(
    const __hip_bfloat16* __restrict__ A, const __hip_bfloat16* __restrict__ Bt,
    const float* __restrict__ bias, OutT* __restrict__ C, int K, int ldc) {
  __shared__ alignas(16) short As[128 * 64];
  __shared__ alignas(16) short Bs[128 * 64];
  const int tid = threadIdx.x;
  const int lane = tid & 63;
  const int w = tid >> 6;
  const int wr = w >> 1, wc = w & 1;
  const int bm = blockIdx.y * 128, bn = blockIdx.x * 128;

  floatx4 zero4 = {0.f, 0.f, 0.f, 0.f};
  floatx4 acc[4][4];
#pragma unroll
  for (int m = 0; m < 4; ++m)
#pragma unroll
    for (int n = 0; n < 4; ++n) acc[m][n] = zero4;

  const int sr = tid >> 3;
  const int skb = (tid & 7) * 16;
  const int frag_kb = (lane >> 4) * 16;

  for (int k0 = 0; k0 < K; k0 += 64) {
    __syncthreads();
#pragma unroll
    for (int p = 0; p < 4; ++p) {
      const int r = sr + p * 32;
      const short8 av = *(const short8*)((const char*)(A + (size_t)(bm + r) * K + k0) + skb);
      const short8 bv = *(const short8*)((const char*)(Bt + (size_t)(bn + r) * K + k0) + skb);
      const int dst = r * 128 + (skb ^ ((r & 7) << 4));
      *(short8*)((char*)As + dst) = av;
      *(short8*)((char*)Bs + dst) = bv;
    }
    __syncthreads();
#pragma unroll
    for (int h = 0; h < 2; ++h) {
      short8 af[4], bf[4];
      const int kb = h * 64 + frag_kb;
#pragma unroll
      for (int m = 0; m < 4; ++m) {
        const int ar = wr * 64 + m * 16 + (lane & 15);
        af[m] = *(const short8*)((const char*)As + ar * 128 + (kb ^ ((ar & 7) << 4)));
      }
#pragma unroll
      for (int n = 0; n < 4; ++n) {
        const int br = wc * 64 + n * 16 + (lane & 15);
        bf[n] = *(const short8*)((const char*)Bs + br * 128 + (kb ^ ((br & 7) << 4)));
      }
#pragma unroll
      for (int m = 0; m < 4; ++m)
#pragma unroll
        for (int n = 0; n < 4; ++n)
          acc[m][n] = __builtin_amdgcn_mfma_f32_16x16x32_bf16(af[m], bf[n], acc[m][n], 0, 0, 0);
    }
  }

  const int col_l = lane & 15;
  const int row_l = (lane >> 4) * 4;
#pragma unroll
  for (int n = 0; n < 4; ++n) {
    const int col = bn + wc * 64 + n * 16 + col_l;
    const float bv = bias[col];
#pragma unroll
    for (int m = 0; m < 4; ++m) {
      const int row0 = bm + wr * 64 + m * 16 + row_l;
#pragma unroll
      for (int r2 = 0; r2 < 4; ++r2) {
        const float v = acc[m][n][r2] + bv;
        if constexpr (sizeof(OutT) == 2)
          C[(size_t)(row0 + r2) * ldc + col] = __float2bfloat16(v);
        else
          C[(size_t)(row0 + r2) * ldc + col] = v;
      }
    }
  }
}

// ---------------------------------------------------------------------------
// RoPE in-place on bf16 qkv. Q heads additionally scaled by 0.125 (=2^-3,
// exact in bf16) so attention needs no score scaling.
// ---------------------------------------------------------------------------
__global__ __launch_bounds__(256) void rope_kernel(__hip_bfloat16* __restrict__ qkv,
                                                   const float* __restrict__ freqs) {
  const int idx = blockIdx.x * 256 + threadIdx.x;
  const int i = idx & 31;
  const int h = (idx >> 5) % 40;
  const int t = idx / (40 * 32);
  const int base = (h < 32) ? h * HD : DM + (h - 32) * HD;
  __hip_bfloat16* p = qkv + (size_t)t * QKV_LD + base;
  const float f = freqs[t * 32 + i];
  float s, c;
  sincosf(f, &s, &c);
  const float x1 = __bfloat162float(p[i]);
  const float x2 = __bfloat162float(p[i + 32]);
  float r1 = x1 * c - x2 * s;
  float r2 = x1 * s + x2 * c;
  if (h < 32) { r1 *= 0.125f; r2 *= 0.125f; }
  p[i]      = __float2bfloat16(r1);
  p[i + 32] = __float2bfloat16(r2);
}

// ---------------------------------------------------------------------------
// MFMA flash attention. Block = (head, 128-row Q block), 4 waves x 32 rows.
// K [64][64] + V^T [64d][64s] staged in XOR-swizzled LDS; Q in registers;
// per-wave P buffer in LDS. Fragment conventions identical to gemm_mfma_bt
// (verified): A/B-frag row = lane&15, k-slice (lane>>4)*8; C/D col = lane&15,
// row = (lane>>4)*4 + reg.
// ---------------------------------------------------------------------------
__global__ __launch_bounds__(256) void attn_mfma_kernel(
    const __hip_bfloat16* __restrict__ qkv, __hip_bfloat16* __restrict__ O) {
  const int bid = blockIdx.x;
  const int head = bid >> 4;
  const int qb = 15 - (bid & 15);     // LJF: big q-blocks dispatch first
  const int kvh = head >> 2;
  const int tid = threadIdx.x;
  const int lane = tid & 63;
  const int w = tid >> 6;
  const int l15 = lane & 15;
  const int lg = lane >> 4;
  const int qbase = qb * 128 + w * 32;   // this wave's first q row

  __shared__ alignas(16) char Ks[64 * 128];       // bf16 [64][64] swizzled
  __shared__ alignas(16) char Vts[64 * 128];      // bf16 [64 d][64 s] swizzled
  __shared__ alignas(16) char Ps[4][32 * 128];    // per-wave P [32][64] swizzled

  // Q fragments: qf[m][kh], row = qbase + m*16 + l15, d = kh*32 + lg*8 .. +8
  short8 qf[2][2];
#pragma unroll
  for (int m = 0; m < 2; ++m)
#pragma unroll
    for (int kh = 0; kh < 2; ++kh)
      qf[m][kh] = *(const short8*)(qkv + (size_t)(qbase + m * 16 + l15) * QKV_LD +
                                   head * HD + kh * 32 + lg * 8);

  floatx4 o_acc[2][4];
  float mrow[2][4], lrow[2][4];
#pragma unroll
  for (int m = 0; m < 2; ++m)
#pragma unroll
    for (int n = 0; n < 4; ++n) o_acc[m][n] = floatx4{0.f, 0.f, 0.f, 0.f};
#pragma unroll
  for (int m = 0; m < 2; ++m)
#pragma unroll
    for (int r = 0; r < 4; ++r) { mrow[m][r] = -INFINITY; lrow[m][r] = 0.f; }

  const __hip_bfloat16* Kg = qkv + DM + kvh * HD;
  const __hip_bfloat16* Vg = qkv + DM + NKV * HD + kvh * HD;
  const int nt = 2 * qb + 2;

  for (int kt = 0; kt < nt; ++kt) {
    const int s0 = kt * 64;
    __syncthreads();
    // --- stage K tile (512 x 16B chunks) ---
#pragma unroll
    for (int p = 0; p < 2; ++p) {
      const int idx = tid + p * 256;
      const int kr = idx >> 3, kc = idx & 7;
      const short8 kv8 = *(const short8*)(Kg + (size_t)(s0 + kr) * QKV_LD + kc * 8);
      *(short8*)(Ks + kr * 128 + ((kc * 16) ^ ((kr & 7) << 4))) = kv8;
    }
    // --- stage V^T: wave w handles d0 = w*16, lane = s ---
    {
      const int vs = tid & 63, d0 = (tid >> 6) * 16;
      const short8 va = *(const short8*)(Vg + (size_t)(s0 + vs) * QKV_LD + d0);
      const short8 vb = *(const short8*)(Vg + (size_t)(s0 + vs) * QKV_LD + d0 + 8);
#pragma unroll
      for (int j = 0; j < 8; ++j) {
        const int rd = d0 + j;
        *(short*)(Vts + rd * 128 + ((vs * 2) ^ ((rd & 7) << 4))) = va[j];
      }
#pragma unroll
      for (int j = 0; j < 8; ++j) {
        const int rd = d0 + 8 + j;
        *(short*)(Vts + rd * 128 + ((vs * 2) ^ ((rd & 7) << 4))) = vb[j];
      }
    }
    __syncthreads();

    if (s0 > qbase + 31) continue;   // tile fully above this wave's diagonal

    // --- QK^T: S[32][64] ---
    floatx4 sacc[2][4];
#pragma unroll
    for (int m = 0; m < 2; ++m)
#pragma unroll
      for (int n = 0; n < 4; ++n) sacc[m][n] = floatx4{0.f, 0.f, 0.f, 0.f};
#pragma unroll
    for (int kh = 0; kh < 2; ++kh) {
      short8 bf[4];
#pragma unroll
      for (int n = 0; n < 4; ++n) {
        const int kr = n * 16 + l15;
        bf[n] = *(const short8*)(Ks + kr * 128 + ((kh * 64 + lg * 16) ^ ((kr & 7) << 4)));
      }
#pragma unroll
      for (int m = 0; m < 2; ++m)
#pragma unroll
        for (int n = 0; n < 4; ++n)
          sacc[m][n] = __builtin_amdgcn_mfma_f32_16x16x32_bf16(qf[m][kh], bf[n], sacc[m][n], 0, 0, 0);
    }
    // --- causal mask (diagonal-overlap tiles only) ---
    if (s0 + 63 > qbase) {
#pragma unroll
      for (int m = 0; m < 2; ++m)
#pragma unroll
        for (int n = 0; n < 4; ++n)
#pragma unroll
          for (int r = 0; r < 4; ++r)
            if (s0 + n * 16 + l15 > qbase + m * 16 + lg * 4 + r)
              sacc[m][n][r] = -INFINITY;
    }
    // --- online softmax + P write ---
#pragma unroll
    for (int m = 0; m < 2; ++m) {
#pragma unroll
      for (int r = 0; r < 4; ++r) {
        float t = fmaxf(fmaxf(sacc[m][0][r], sacc[m][1][r]),
                        fmaxf(sacc[m][2][r], sacc[m][3][r]));
        t = fmaxf(t, __shfl_xor(t, 1));
        t = fmaxf(t, __shfl_xor(t, 2));
        t = fmaxf(t, __shfl_xor(t, 4));
        t = fmaxf(t, __shfl_xor(t, 8));
        const float mn = fmaxf(mrow[m][r], t);
        const float corr = __expf(mrow[m][r] - mn);   // -inf first tile -> 0
        mrow[m][r] = mn;
        float ls = 0.f;
        float pv[4];
#pragma unroll
        for (int n = 0; n < 4; ++n) {
          pv[n] = __expf(sacc[m][n][r] - mn);         // masked -inf -> 0
          ls += pv[n];
        }
        ls += __shfl_xor(ls, 1);
        ls += __shfl_xor(ls, 2);
        ls += __shfl_xor(ls, 4);
        ls += __shfl_xor(ls, 8);
        lrow[m][r] = lrow[m][r] * corr + ls;
#pragma unroll
        for (int n = 0; n < 4; ++n) o_acc[m][n][r] *= corr;
        const int prow = m * 16 + lg * 4 + r;
#pragma unroll
        for (int n = 0; n < 4; ++n)
          *(__hip_bfloat16*)(Ps[w] + prow * 128 +
                             (((n * 16 + l15) * 2) ^ ((prow & 7) << 4))) =
              __float2bfloat16(pv[n]);
      }
    }
    // --- PV: O[32][64] += P[32][64] @ V[64][64] (same-wave P buffer, no barrier) ---
#pragma unroll
    for (int kh = 0; kh < 2; ++kh) {
      short8 pf[2];
#pragma unroll
      for (int m = 0; m < 2; ++m) {
        const int pr = m * 16 + l15;
        pf[m] = *(const short8*)(Ps[w] + pr * 128 + ((kh * 64 + lg * 16) ^ ((pr & 7) << 4)));
      }
      short8 vf[4];
#pragma unroll
      for (int n = 0; n < 4; ++n) {
        const int vr = n * 16 + l15;
        vf[n] = *(const short8*)(Vts + vr * 128 + ((kh * 64 + lg * 16) ^ ((vr & 7) << 4)));
      }
#pragma unroll
      for (int m = 0; m < 2; ++m)
#pragma unroll
        for (int n = 0; n < 4; ++n)
          o_acc[m][n] = __builtin_amdgcn_mfma_f32_16x16x32_bf16(pf[m], vf[n], o_acc[m][n], 0, 0, 0);
    }
  }

  // --- epilogue: O / l -> bf16 ---
#pragma unroll
  for (int m = 0; m < 2; ++m) {
    float inv[4];
#pragma unroll
    for (int r = 0; r < 4; ++r) inv[r] = 1.f / lrow[m][r];
#pragma unroll
    for (int n = 0; n < 4; ++n)
#pragma unroll
      for (int r = 0; r < 4; ++r)
        O[(size_t)(qbase + m * 16 + lg * 4 + r) * DM + head * HD + n * 16 + l15] =
            __float2bfloat16(o_acc[m][n][r] * inv[r]);
  }
}

// ---------------------------------------------------------------------------
extern "C" void kernel_launch(void* const* d_in, const int* in_sizes, int n_in,
                              void* d_out, int out_size, void* d_ws, size_t ws_size,
                              hipStream_t stream) {
  const float* x     = (const float*)d_in[0];
  const float* Wq    = (const float*)d_in[1];
  const float* bq    = (const float*)d_in[2];
  const float* Wk    = (const float*)d_in[3];
  const float* bk    = (const float*)d_in[4];
  const float* Wv    = (const float*)d_in[5];
  const float* bv    = (const float*)d_in[6];
  const float* Wo    = (const float*)d_in[7];
  const float* bo    = (const float*)d_in[8];
  const float* freqs = (const float*)d_in[9];
  float* out = (float*)d_out;

  // ws layout (peak 33.6 MB):
  //   [0)           qkv bf16 [2048][3072]            12,582,912 B
  //   [12,582,912)  wt  bf16 [3072][2048] (QKV^T)    12,582,912 B  -> reused for Wo^T
  //   [25,165,824)  xb  bf16 [2048][2048]             8,388,608 B  -> reused for attn out
  //   [33,554,432)  bias_cat f32 [3072]                   12,288 B
  char* ws = (char*)d_ws;
  __hip_bfloat16* qkv  = (__hip_bfloat16*)ws;
  __hip_bfloat16* wt   = (__hip_bfloat16*)(ws + 12582912);
  __hip_bfloat16* xb   = (__hip_bfloat16*)(ws + 25165824);
  __hip_bfloat16* obuf = xb;   // alias: xb dead after QKV GEMM
  __hip_bfloat16* wot  = wt;   // alias: wt dead after QKV GEMM
  float*          bcat = (float*)(ws + 33554432);

  const dim3 blk(256);

  cast_bf16_kernel<<<(DM * T_CTX) / (256 * 8), blk, 0, stream>>>(x, xb);
  transpose_cast_kernel<<<dim3(32, 32), blk, 0, stream>>>(Wq, wt, 2048, 2048);
  transpose_cast_kernel<<<dim3(8, 32),  blk, 0, stream>>>(Wk, wt + (size_t)2048 * 2048, 512, 2048);
  transpose_cast_kernel<<<dim3(8, 32),  blk, 0, stream>>>(Wv, wt + (size_t)2560 * 2048, 512, 2048);
  hipMemcpyAsync(bcat,        bq, 2048 * 4, hipMemcpyDeviceToDevice, stream);
  hipMemcpyAsync(bcat + 2048, bk, 512 * 4,  hipMemcpyDeviceToDevice, stream);
  hipMemcpyAsync(bcat + 2560, bv, 512 * 4,  hipMemcpyDeviceToDevice, stream);

  // fused QKV projection -> bf16 qkv (ldc 3072)
  gemm_mfma_bt<__hip_bfloat16><<<dim3(3072 / 128, 2048 / 128), blk, 0, stream>>>(
      xb, wt, bcat, qkv, DM, QKV_LD);

  // RoPE (bf16 in place; Q scaled by 2^-3)
  rope_kernel<<<(T_CTX * 40 * 32) / 256, blk, 0, stream>>>(qkv, freqs);

  // Wo^T (reuses wt region)
  transpose_cast_kernel<<<dim3(32, 32), blk, 0, stream>>>(Wo, wot, 2048, 2048);

  // MFMA flash attention -> obuf bf16 [2048][2048]
  attn_mfma_kernel<<<dim3(NQ * 16), blk, 0, stream>>>(qkv, obuf);

  // output projection -> d_out (f32)
  gemm_mfma_bt<float><<<dim3(2048 / 128, 2048 / 128), blk, 0, stream>>>(
      obuf, wot, bo, out, DM, DM);
}